// Round 16
// baseline (569.959 us; speedup 1.0000x reference)
//
#include <hip/hip_runtime.h>
#include <math.h>
#include <string.h>

// V2VNetFusion on MI355X, round 20: r16 minus weight-LDS (L2-direct
// weights).
// Rationale (Common-mistake #7 / m169): weights are 36KB per (grp,kb),
// identical for 275-1100 blocks -> permanently L2-hot. Staging them
// cost 36.9KB LDS + an exposed single-buffered DMA per kb (the r17/r18
// spill saga tried and failed to hide it). This round deletes s_w /
// stage_w entirely; aw[cf] reads come straight from global pw
// (wave-uniform address, 1KB-coalesced, L2-served -- NOT the r12
// failure mode, which was per-block-streamed divergent INPUT operands).
// Wins: LDS = input dbuf only (43520 B @TW32, 23040 @TW16) ->
// 3 blocks/CU = 6 waves/SIMD on the big dispatches (the only lever
// that has ever moved this workload: 2->4 w/SIMD was +33us); GATES-t>0
// 550 blocks now fully co-resident (<=768 slots, no straggler round);
// 2 barriers per kb-pair instead of 4; weight-DMA exposure gone.
// Everything else r16: TW template (32: MSG/GATES-t>0; 16: CAND all t,
// GATES-t0), 8-row tiles, 512thr/8 waves, wave = 1 row x TW (P=TW/16),
// CF=4, pipelined input DMA (global_load_lds, inverse-XOR-swizzled
// source, linear LDS dest), zero-page halo, setprio on MFMA cluster.
#define HH 200
#define WW 352
#define HWSZ (HH*WW)          // 70400
#define CHW (64L*HWSZ)        // one (64,H,W) tensor, elems

enum { EPI_MSG=0, EPI_GATES=1, EPI_CAND=2 };

typedef __attribute__((ext_vector_type(8))) _Float16 f16x8;
typedef __attribute__((ext_vector_type(4))) float f32x4;
typedef __attribute__((ext_vector_type(4))) unsigned int uint4v;
typedef __attribute__((ext_vector_type(4))) unsigned short ushort4v;

__device__ __forceinline__ unsigned short f2h(float f) {
    _Float16 h = (_Float16)f;                    // v_cvt_f16_f32 (RTE)
    return __builtin_bit_cast(unsigned short, h);
}
__device__ __forceinline__ float h2f(unsigned short u) {
    return (float)__builtin_bit_cast(_Float16, u);
}

// global->LDS DMA, 16B per lane. LDS dest = wave-uniform base + lane*16.
__device__ __forceinline__ void load_lds16(const unsigned short* g,
                                           unsigned short* l) {
    __builtin_amdgcn_global_load_lds(
        (const __attribute__((address_space(1))) unsigned int*)g,
        (__attribute__((address_space(3))) unsigned int*)l, 16, 0, 0);
}

// Prepack conv weights to f16, lane-major layout, CF=4:
// chunk(cogrp64,kb) = [sh(9)][cf(4)][lane(64)][8ch] = 18432 f16.
// lane = q*16+n16 -> co = cogrp*64 + cf*16+n16, ch = q*8+j.
// msg: 1x4, gates: 2x6, cand: 1x6 chunks. Tail threads zero the 256B
// zero-page (reg source for OOB halo).
__global__ void prepack_k(const float* __restrict__ mw,
                          const float* __restrict__ gw,
                          const float* __restrict__ cw,
                          unsigned short* __restrict__ pw,
                          unsigned short* __restrict__ zp)
{
    const int MSG_I = 4*18432;        // 73728
    const int GAT_I = 12*18432;       // 221184
    const int CAN_I = 6*18432;        // 110592
    const int TOTAL = MSG_I + GAT_I + CAN_I;   // 405504
    int idx = blockIdx.x*256 + threadIdx.x;
    if (idx >= TOTAL) {
        int r = idx - TOTAL;
        if (r < 128) zp[r] = 0;
        return;
    }
    const float* w; int cin, nkb, rel; unsigned short* base;
    if (idx < MSG_I)              { w=mw; cin=128; nkb=4; rel=idx;              base=pw; }
    else if (idx < MSG_I+GAT_I)   { w=gw; cin=192; nkb=6; rel=idx-MSG_I;        base=pw+73728; }
    else                          { w=cw; cin=192; nkb=6; rel=idx-MSG_I-GAT_I;  base=pw+294912; }
    int chunk = rel / 18432, r = rel - chunk*18432;
    int j = r & 7, lane = (r >> 3) & 63, cfsh = r >> 9;   // cfsh 0..35
    int cf = cfsh & 3, sh = cfsh >> 2;
    int q = lane >> 4, n16 = lane & 15;
    int co_l = cf*16 + n16, ch = q*8 + j;
    int cogrp = chunk / nkb, kb = chunk - cogrp*nkb;
    float f = w[(((long)(cogrp*64 + co_l))*cin + kb*32 + ch)*9 + sh];
    base[(size_t)chunk*18432 + r] = f2h(f);
}

// Convert x (2 agents x 4 t) fp32 planar -> f16 interleaved [t][half][pix][32].
__global__ void convert_all_k(const float* __restrict__ x,
                              unsigned short* __restrict__ xb0_all,
                              unsigned short* __restrict__ xb1_all)
{
    int idx = blockIdx.x*256 + threadIdx.x;      // 4,505,600 total
    int cp   = idx & 15;
    int rest = idx >> 4;
    int px4  = rest % 17600;
    int r2   = rest / 17600;                      // 0..15
    int hb = r2 & 1, ag = (r2 >> 1) & 1, t = r2 >> 2;
    const float* src = x + ((size_t)(ag*4 + t))*CHW
                         + (size_t)(hb*32 + 2*cp)*HWSZ + (size_t)px4*4;
    float4 a = *(const float4*)src;
    float4 b = *(const float4*)(src + HWSZ);
    unsigned int* dst = (unsigned int*)((ag ? xb1_all : xb0_all)
                        + (size_t)t*CHW + (size_t)hb*HWSZ*32) + (size_t)px4*64 + cp;
    dst[0]  = (unsigned)f2h(a.x) | ((unsigned)f2h(b.x) << 16);
    dst[16] = (unsigned)f2h(a.y) | ((unsigned)f2h(b.y) << 16);
    dst[32] = (unsigned)f2h(a.z) | ((unsigned)f2h(b.z) << 16);
    dst[48] = (unsigned)f2h(a.w) | ((unsigned)f2h(b.w) << 16);
}

// Block: 64 out-ch x (8 rows x TW cols), 512 thr = 8 waves; wave wv =
// row wv (P = TW/16 col-halves), CF=4.
// LDS: 2x input [10][TW+2][32] f16 XOR-swz ONLY (43520 B @TW32 /
// 23040 @TW16) -> 3 blocks/CU (24 waves, 6 w/SIMD) on TW=32.
// Weights: direct-from-global (L2-hot, wave-coalesced 1KB reads).
template<int EPI, int TW>
__global__ __launch_bounds__(512, 4)
void conv_mfma_k(const unsigned short* __restrict__ seg0b,
                 const unsigned short* __restrict__ seg1b,
                 const unsigned short* __restrict__ seg2b,
                 int nkb, int nkb_stride, int grp_base,
                 const unsigned short* __restrict__ pw,
                 const unsigned short* __restrict__ zp,
                 const float* __restrict__ bias,
                 const unsigned short* e_hb,     // f16 interl. h_{t-1} (null @t=0)
                 const unsigned short* __restrict__ e_updb, // CAND: upd f16 interl.
                 float* out_f,                   // CAND: out[t] fp32 planar
                 unsigned short* out_b,          // MSG: aggb(t<3) GATES: rhb CAND: hb
                 unsigned short* out_b2)         // MSG: aggb3    GATES: updb
{
    constexpr int ROWS   = 8;                    // tile rows
    constexpr int TC     = TW + 2;               // tile pitch (34 / 18)
    constexpr int PP     = TW / 16;              // px-frags per wave (2 / 1)
    constexpr int HSLOTS = (2*TC + 16)*4;        // halo granules (336 / 208)

    __shared__ unsigned short s_in0[(ROWS+2)*TC*32];
    __shared__ unsigned short s_in1[(ROWS+2)*TC*32];

    const int tid  = threadIdx.x;
    const int lane = tid & 63;
    const int wv   = tid >> 6;                   // 0..7
    const int n16  = lane & 15;
    const int q    = lane >> 4;

    int grp, ts = 0;
    if (EPI == EPI_MSG) { ts = blockIdx.z; grp = 0; }
    else                { grp = blockIdx.z + grp_base; }

    const unsigned short* s0 = seg0b + (EPI==EPI_MSG ? (size_t)ts*CHW : 0);
    const unsigned short* s1 = seg1b + (EPI==EPI_MSG ? (size_t)ts*CHW : 0);
    unsigned short* ob = out_b;
    if (EPI == EPI_MSG) ob = (ts < 3) ? out_b + (size_t)ts*CHW : out_b2;

    const int x0p = blockIdx.x * TW;
    const int y0  = blockIdx.y * ROWS;

    // ---- halo descriptor: ring = (2*TC+16) pos x 4 granules; thread
    // tid (< HSLOTS) owns one slot.
    int hdst = 0; size_t hsrc = 0; bool hval = false;
    const bool hact = (tid < HSLOTS);
    if (hact) {
        int hp = tid >> 2, gs = tid & 3;
        int row, col;
        if (hp < TC)        { row = 0;      col = hp; }
        else if (hp < 2*TC) { row = ROWS+1; col = hp - TC; }
        else { int k = hp - 2*TC; row = 1 + (k >> 1); col = (k & 1)*(TC-1); }
        int pos = row*TC + col;
        int gy = y0 + row - 1, gx = x0p + col - 1;
        hdst = (pos << 5) + (gs << 3);
        int g = (gs ^ pos ^ (pos >> 2)) & 3;
        if ((unsigned)gy < (unsigned)HH && (unsigned)gx < (unsigned)WW) {
            hval = true;
            hsrc = ((size_t)(gy*WW + gx) << 5) + (size_t)(g << 3);
        }
    }

    auto srcof = [&](int kb) -> const unsigned short* {
        return ((kb < 2) ? s0 : (kb < 4) ? s1 : seg2b) + (size_t)(kb & 1)*HWSZ*32;
    };

    auto halo_load = [&](int kb, uint4v& h) {
        const unsigned short* src = srcof(kb);
        if (hact) h = *(const uint4v*)(hval ? src + hsrc : zp);
    };
    auto halo_write = [&](unsigned short* bin, const uint4v& h) {
        if (hact) *(uint4v*)&bin[hdst] = h;
    };

    // interior: 8 rows x PP col-halves = 8*PP wave-chunks, PP per wave
    // (full 64B granules, inverse-swizzled source, linear LDS dest).
    auto stage_in = [&](int kb, unsigned short* bin) {
        const unsigned short* src = srcof(kb);
#pragma unroll
        for (int j = 0; j < PP; ++j) {
            const int c    = wv + 8*j;           // 0..8*PP-1
            const int row  = (PP == 2) ? 1 + (c >> 1) : 1 + c;
            const int colh = (PP == 2) ? (c & 1) : 0;
            const int gy   = y0 + row - 1;       // in [0,199] always
            const int p0   = row*TC + 1 + colh*16;
            const int pl   = p0 + (lane >> 2);
            const int g    = ((lane & 3) ^ pl ^ (pl >> 2)) & 3;
            const int gx   = x0p + colh*16 + (lane >> 2);
            load_lds16(src + (((size_t)(gy*WW + gx)) << 5) + (g << 3),
                       &bin[(size_t)p0 << 5]);
        }
    };

    f32x4 acc[4][PP];
#pragma unroll
    for (int cf=0; cf<4; ++cf)
#pragma unroll
        for (int p=0; p<PP; ++p) acc[cf][p] = (f32x4){0.f,0.f,0.f,0.f};

    // weights direct-from-global: wave-uniform base, lane-major 1KB
    // coalesced reads, L2-hot (36KB/chunk shared by all blocks of grp).
    auto compute = [&](const unsigned short* sin, int kb) {
        const unsigned short* wsrc = pw + (size_t)(grp*nkb_stride + kb)*18432;
        __builtin_amdgcn_s_setprio(1);
#pragma unroll
        for (int ky = 0; ky < 3; ++ky) {
#pragma unroll
            for (int kx = 0; kx < 3; ++kx) {
                const int sh = ky*3 + kx;
                f16x8 aw[4];
#pragma unroll
                for (int cf = 0; cf < 4; ++cf)
                    aw[cf] = *(const f16x8*)&wsrc[((sh*4 + cf)*64 + lane)*8];
#pragma unroll
                for (int p = 0; p < PP; ++p) {
                    const int rl = wv + ky;
                    const int cl = 16*p + n16 + kx;
                    const int pos = rl*TC + cl;
                    const int sw = (q ^ pos ^ (pos >> 2)) & 3;
                    f16x8 bfr = *(const f16x8*)&sin[(pos << 5) + (sw << 3)];
#pragma unroll
                    for (int cf = 0; cf < 4; ++cf)
                        acc[cf][p] = __builtin_amdgcn_mfma_f32_16x16x32_f16(
                                         aw[cf], bfr, acc[cf][p], 0, 0, 0);
                }
            }
        }
        __builtin_amdgcn_s_setprio(0);
    };

    uint4v h0, h1;
    stage_in(0, s_in0);          // prologue: kb=0 input DMA + halo
    halo_load(0, h0);

    for (int kb = 0; kb < nkb; kb += 2) {      // nkb even (4 or 6)
        // ===== phase A: buf0 = kb
        halo_write(s_in0, h0);                 // waits h0 (vmcnt dep)
        __syncthreads();                       // kb DMA landed + halo visible;
                                               // all waves done reading s_in1(kb-1)
        halo_load(kb + 1, h1);
        stage_in(kb + 1, s_in1);               // flies across compute
        __builtin_amdgcn_sched_barrier(0);
        compute(s_in0, kb);
        // ===== phase B: buf1 = kb+1
        halo_write(s_in1, h1);
        __syncthreads();                       // kb+1 DMA landed; done with s_in0
        if (kb + 2 < nkb) {
            halo_load(kb + 2, h0);
            stage_in(kb + 2, s_in0);
            __builtin_amdgcn_sched_barrier(0);
        }
        compute(s_in1, kb + 1);
    }

    // ---- epilogue. C/D: pixel = lane&15, co = (lane>>4)*4 + reg
#pragma unroll
    for (int cf = 0; cf < 4; ++cf) {
        const int half   = cf >> 1;                // 32-ch half within co64
        const int cobase = grp*64 + cf*16 + q*4;   // global co of reg 0
        const int cmod   = (cf & 1)*16 + q*4;      // co within 32-plane
#pragma unroll
        for (int p = 0; p < PP; ++p) {
            const int row = y0 + wv;               // always < 200
            const int col = x0p + 16*p + n16;
            const long pix = (long)row*WW + col;
            const size_t iidx = (((size_t)half*HWSZ + pix) << 5) + cmod;
            float v[4];
#pragma unroll
            for (int r = 0; r < 4; ++r) v[r] = acc[cf][p][r] + bias[cobase + r];

            if (EPI == EPI_MSG) {
                ushort4v xv = *(const ushort4v*)&s0[iidx];
                ushort4v s;
#pragma unroll
                for (int r = 0; r < 4; ++r)
                    s[r] = f2h(0.5f*(h2f(xv[r]) + v[r]));
                *(ushort4v*)&ob[iidx] = s;
            } else if (EPI == EPI_GATES) {
                if (grp == 0) {  // reset block -> rh = sigmoid * h
                    ushort4v hv = e_hb ? *(const ushort4v*)&e_hb[iidx]
                                       : (ushort4v){0,0,0,0};
                    ushort4v s;
#pragma unroll
                    for (int r = 0; r < 4; ++r) {
                        float g = 1.f/(1.f + __expf(-v[r]));
                        s[r] = f2h(g * h2f(hv[r]));
                    }
                    *(ushort4v*)&out_b[iidx] = s;
                } else {         // update block -> updb
                    ushort4v s;
#pragma unroll
                    for (int r = 0; r < 4; ++r)
                        s[r] = f2h(1.f/(1.f + __expf(-v[r])));
                    *(ushort4v*)&out_b2[iidx] = s;
                }
            } else {             // CAND: h_next -> out fp32 planar + hb f16
                ushort4v uv = *(const ushort4v*)&e_updb[iidx];
                ushort4v hv = e_hb ? *(const ushort4v*)&e_hb[iidx]
                                   : (ushort4v){0,0,0,0};
                ushort4v s;
#pragma unroll
                for (int r = 0; r < 4; ++r) {
                    float cnm = tanhf(v[r]);
                    float u   = h2f(uv[r]);
                    float hn  = (1.f - u)*h2f(hv[r]) + u*cnm;
                    out_f[(long)(cobase+r)*HWSZ + pix] = hn;
                    s[r] = f2h(hn);
                }
                *(ushort4v*)&out_b[iidx] = s;
            }
        }
    }
}

// ws (u16 units): xb0_all 4C | aggb3 C | rhb C | updb C | hb C | pw 405504
//   | zp 128  = 72.9 MB.   d_out aliases: xb1_all = out[0..1] (dead until
//   step 0 writes out[0]), aggb[0..2] = out[2..3].
extern "C" void kernel_launch(void* const* d_in, const int* in_sizes, int n_in,
                              void* d_out, int out_size, void* d_ws, size_t ws_size,
                              hipStream_t stream)
{
    const float* x       = (const float*)d_in[0];
    const float* msg_w   = (const float*)d_in[1];
    const float* msg_b   = (const float*)d_in[2];
    const float* gates_w = (const float*)d_in[3];
    const float* gates_b = (const float*)d_in[4];
    const float* can_w   = (const float*)d_in[5];
    const float* can_b   = (const float*)d_in[6];
    float* out = (float*)d_out;

    unsigned short* W       = (unsigned short*)d_ws;
    unsigned short* xb0_all = W;                  // [4][2][HWSZ][32]
    unsigned short* aggb3   = W + 4*CHW;
    unsigned short* rhb     = W + 5*CHW;
    unsigned short* updb    = W + 6*CHW;
    unsigned short* hb      = W + 7*CHW;
    unsigned short* pw      = W + 8*CHW;          // 405504 u16
    unsigned short* pw_msg  = pw;                 // cf4 msg   (1x4)
    unsigned short* pw_gat  = pw + 73728;         // cf4 gates (2x6)
    unsigned short* pw_can  = pw + 294912;        // cf4 cand  (1x6)
    unsigned short* zp      = pw + 405504;        // 128 u16 zero page

    unsigned short* outU16   = (unsigned short*)d_out;
    unsigned short* xb1_all  = outU16;            // 4*CHW u16 = out[0..1]
    unsigned short* aggbase  = outU16 + 4*CHW;    // aggb[0..2] = out[2..3]

    prepack_k<<<dim3(1585), dim3(256), 0, stream>>>(msg_w, gates_w, can_w, pw, zp);
    convert_all_k<<<dim3(17600), dim3(256), 0, stream>>>(x, xb0_all, xb1_all);

    // msg for all 4 t in one dispatch: Cin=[x0|x1], Cout=64 -> aggb[t].
    // TW=32: 1100 blocks, 3/CU, 6 waves/SIMD.
    conv_mfma_k<EPI_MSG,32><<<dim3(11,25,4), dim3(512), 0, stream>>>(
        xb0_all, xb1_all, nullptr, 4, 4, 0, pw_msg, zp, msg_b,
        nullptr, nullptr, nullptr, aggbase, aggb3);

    for (int t = 0; t < 4; ++t) {
        const unsigned short* xt  = xb0_all + (size_t)t*CHW;
        const unsigned short* agt = (t < 3) ? aggbase + (size_t)t*CHW : aggb3;
        const unsigned short* hprev = t ? hb : nullptr;

        if (t == 0) {
            // t=0: h==0 -> reset*h==0 and CAND(nkb=4) never reads rhb;
            // update half only (grp_base=1). TW=16 -> 550 blocks.
            conv_mfma_k<EPI_GATES,16><<<dim3(22,25,1), dim3(512), 0, stream>>>(
                xt, agt, nullptr, 4, 6, 1, pw_gat, zp, gates_b,
                nullptr, nullptr, nullptr, rhb, updb);
        } else {
            // gates: Cin=[x|agg|h], Cout=128; z=0 reset / z=1 update.
            // TW=32: 550 blocks, fully co-resident at 3/CU.
            conv_mfma_k<EPI_GATES,32><<<dim3(11,25,2), dim3(512), 0, stream>>>(
                xt, agt, hb, 6, 6, 0, pw_gat, zp, gates_b,
                hprev, nullptr, nullptr, rhb, updb);
        }
        // cand: Cin=[x|agg|rh], Cout=64 -> out[t] fp32 + hb f16.
        // TW=16 -> 550 blocks.
        conv_mfma_k<EPI_CAND,16><<<dim3(22,25,1), dim3(512), 0, stream>>>(
            xt, agt, rhb, t ? 6 : 4, 6, 0, pw_can, zp, can_b,
            hprev, updb, out + (size_t)t*CHW, hb, nullptr);
    }
}

// Round 17
// 372.601 us; speedup vs baseline: 1.5297x; 1.5297x over previous
//
#include <hip/hip_runtime.h>
#include <math.h>
#include <string.h>

// V2VNetFusion on MI355X, round 21 (FINAL): restore r16 (373.6us best,
// replicated 374.7 in r19).
// r20 post-mortem: L2-direct weights REFUTED (570us, MfmaUtil 14%) --
// even wave-uniform L2-hot weight reads serialize vmcnt waits with the
// MFMA stream. Combined with r12: BOTH MFMA operand streams must come
// from LDS on gfx950; global-direct is never viable for operands.
// Final configuration (r16):
//  - TW template: 32 (MSG, GATES t>0) / 16 (CAND all t, GATES t0);
//    8-row tiles, 512thr = 8 waves, wave = 1 row x TW cols, CF=4,
//    P = TW/16. LDS = input dbuf + single weight buf (80384 / 59904 B)
//    -> 2 blocks/CU = 16 waves/CU = 4 waves/SIMD everywhere.
//  - Pipelined input DMA (global_load_lds, inverse-XOR-swizzled source,
//    linear LDS dest), zero-page halo, setprio around MFMA cluster.
//  - Ladder: 481 -> 428 (cf4+pipe) -> 406 (WR) -> 373.9 (4 w/SIMD) ->
//    373.6 (TW split). ~600 TF ~= 24% dense f16 peak, at the 2-barrier
//    schedule's ~28% structural ceiling (m233). Refuted beyond it:
//    K16 MFMA, reg-staging (spills), raw-barrier pipeline (hang),
//    CF=2 ratio ceiling, direct-global operands, L2-direct weights.
#define HH 200
#define WW 352
#define HWSZ (HH*WW)          // 70400
#define CHW (64L*HWSZ)        // one (64,H,W) tensor, elems

enum { EPI_MSG=0, EPI_GATES=1, EPI_CAND=2 };

typedef __attribute__((ext_vector_type(8))) _Float16 f16x8;
typedef __attribute__((ext_vector_type(4))) float f32x4;
typedef __attribute__((ext_vector_type(4))) unsigned int uint4v;
typedef __attribute__((ext_vector_type(4))) unsigned short ushort4v;

__device__ __forceinline__ unsigned short f2h(float f) {
    _Float16 h = (_Float16)f;                    // v_cvt_f16_f32 (RTE)
    return __builtin_bit_cast(unsigned short, h);
}
__device__ __forceinline__ float h2f(unsigned short u) {
    return (float)__builtin_bit_cast(_Float16, u);
}

// global->LDS DMA, 16B per lane. LDS dest = wave-uniform base + lane*16.
__device__ __forceinline__ void load_lds16(const unsigned short* g,
                                           unsigned short* l) {
    __builtin_amdgcn_global_load_lds(
        (const __attribute__((address_space(1))) unsigned int*)g,
        (__attribute__((address_space(3))) unsigned int*)l, 16, 0, 0);
}

// Prepack conv weights to f16, LDS-ready lane-major layout, CF=4:
// chunk(cogrp64,kb) = [sh(9)][cf(4)][lane(64)][8ch] = 18432 f16.
// lane = q*16+n16 -> co = cogrp*64 + cf*16+n16, ch = q*8+j.
// msg: 1x4, gates: 2x6, cand: 1x6 chunks. Tail threads zero the 256B
// zero-page (reg source for OOB halo).
__global__ void prepack_k(const float* __restrict__ mw,
                          const float* __restrict__ gw,
                          const float* __restrict__ cw,
                          unsigned short* __restrict__ pw,
                          unsigned short* __restrict__ zp)
{
    const int MSG_I = 4*18432;        // 73728
    const int GAT_I = 12*18432;       // 221184
    const int CAN_I = 6*18432;        // 110592
    const int TOTAL = MSG_I + GAT_I + CAN_I;   // 405504
    int idx = blockIdx.x*256 + threadIdx.x;
    if (idx >= TOTAL) {
        int r = idx - TOTAL;
        if (r < 128) zp[r] = 0;
        return;
    }
    const float* w; int cin, nkb, rel; unsigned short* base;
    if (idx < MSG_I)              { w=mw; cin=128; nkb=4; rel=idx;              base=pw; }
    else if (idx < MSG_I+GAT_I)   { w=gw; cin=192; nkb=6; rel=idx-MSG_I;        base=pw+73728; }
    else                          { w=cw; cin=192; nkb=6; rel=idx-MSG_I-GAT_I;  base=pw+294912; }
    int chunk = rel / 18432, r = rel - chunk*18432;
    int j = r & 7, lane = (r >> 3) & 63, cfsh = r >> 9;   // cfsh 0..35
    int cf = cfsh & 3, sh = cfsh >> 2;
    int q = lane >> 4, n16 = lane & 15;
    int co_l = cf*16 + n16, ch = q*8 + j;
    int cogrp = chunk / nkb, kb = chunk - cogrp*nkb;
    float f = w[(((long)(cogrp*64 + co_l))*cin + kb*32 + ch)*9 + sh];
    base[(size_t)chunk*18432 + r] = f2h(f);
}

// Convert x (2 agents x 4 t) fp32 planar -> f16 interleaved [t][half][pix][32].
__global__ void convert_all_k(const float* __restrict__ x,
                              unsigned short* __restrict__ xb0_all,
                              unsigned short* __restrict__ xb1_all)
{
    int idx = blockIdx.x*256 + threadIdx.x;      // 4,505,600 total
    int cp   = idx & 15;
    int rest = idx >> 4;
    int px4  = rest % 17600;
    int r2   = rest / 17600;                      // 0..15
    int hb = r2 & 1, ag = (r2 >> 1) & 1, t = r2 >> 2;
    const float* src = x + ((size_t)(ag*4 + t))*CHW
                         + (size_t)(hb*32 + 2*cp)*HWSZ + (size_t)px4*4;
    float4 a = *(const float4*)src;
    float4 b = *(const float4*)(src + HWSZ);
    unsigned int* dst = (unsigned int*)((ag ? xb1_all : xb0_all)
                        + (size_t)t*CHW + (size_t)hb*HWSZ*32) + (size_t)px4*64 + cp;
    dst[0]  = (unsigned)f2h(a.x) | ((unsigned)f2h(b.x) << 16);
    dst[16] = (unsigned)f2h(a.y) | ((unsigned)f2h(b.y) << 16);
    dst[32] = (unsigned)f2h(a.z) | ((unsigned)f2h(b.z) << 16);
    dst[48] = (unsigned)f2h(a.w) | ((unsigned)f2h(b.w) << 16);
}

// Block: 64 out-ch x (8 rows x TW cols), 512 thr = 8 waves; wave wv =
// row wv (P = TW/16 col-halves), CF=4.
// LDS: 2x input [10][TW+2][32] f16 XOR-swz + 1x weights [9][4][64][8]
// (36864 B).  TW=32: 80384 B, TW=16: 59904 B -> 2 blocks/CU, 4 w/SIMD.
template<int EPI, int TW>
__global__ __launch_bounds__(512, 4)
void conv_mfma_k(const unsigned short* __restrict__ seg0b,
                 const unsigned short* __restrict__ seg1b,
                 const unsigned short* __restrict__ seg2b,
                 int nkb, int nkb_stride, int grp_base,
                 const unsigned short* __restrict__ pw,
                 const unsigned short* __restrict__ zp,
                 const float* __restrict__ bias,
                 const unsigned short* e_hb,     // f16 interl. h_{t-1} (null @t=0)
                 const unsigned short* __restrict__ e_updb, // CAND: upd f16 interl.
                 float* out_f,                   // CAND: out[t] fp32 planar
                 unsigned short* out_b,          // MSG: aggb(t<3) GATES: rhb CAND: hb
                 unsigned short* out_b2)         // MSG: aggb3    GATES: updb
{
    constexpr int ROWS   = 8;                    // tile rows
    constexpr int TC     = TW + 2;               // tile pitch (34 / 18)
    constexpr int PP     = TW / 16;              // px-frags per wave (2 / 1)
    constexpr int HSLOTS = (2*TC + 16)*4;        // halo granules (336 / 208)

    __shared__ unsigned short s_in0[(ROWS+2)*TC*32];
    __shared__ unsigned short s_in1[(ROWS+2)*TC*32];
    __shared__ unsigned short s_w[9*4*64*8];           // 36864 B

    const int tid  = threadIdx.x;
    const int lane = tid & 63;
    const int wv   = tid >> 6;                   // 0..7
    const int n16  = lane & 15;
    const int q    = lane >> 4;

    int grp, ts = 0;
    if (EPI == EPI_MSG) { ts = blockIdx.z; grp = 0; }
    else                { grp = blockIdx.z + grp_base; }

    const unsigned short* s0 = seg0b + (EPI==EPI_MSG ? (size_t)ts*CHW : 0);
    const unsigned short* s1 = seg1b + (EPI==EPI_MSG ? (size_t)ts*CHW : 0);
    unsigned short* ob = out_b;
    if (EPI == EPI_MSG) ob = (ts < 3) ? out_b + (size_t)ts*CHW : out_b2;

    const int x0p = blockIdx.x * TW;
    const int y0  = blockIdx.y * ROWS;

    // ---- halo descriptor: ring = (2*TC+16) pos x 4 granules; thread
    // tid (< HSLOTS) owns one slot.
    int hdst = 0; size_t hsrc = 0; bool hval = false;
    const bool hact = (tid < HSLOTS);
    if (hact) {
        int hp = tid >> 2, gs = tid & 3;
        int row, col;
        if (hp < TC)        { row = 0;      col = hp; }
        else if (hp < 2*TC) { row = ROWS+1; col = hp - TC; }
        else { int k = hp - 2*TC; row = 1 + (k >> 1); col = (k & 1)*(TC-1); }
        int pos = row*TC + col;
        int gy = y0 + row - 1, gx = x0p + col - 1;
        hdst = (pos << 5) + (gs << 3);
        int g = (gs ^ pos ^ (pos >> 2)) & 3;
        if ((unsigned)gy < (unsigned)HH && (unsigned)gx < (unsigned)WW) {
            hval = true;
            hsrc = ((size_t)(gy*WW + gx) << 5) + (size_t)(g << 3);
        }
    }

    auto srcof = [&](int kb) -> const unsigned short* {
        return ((kb < 2) ? s0 : (kb < 4) ? s1 : seg2b) + (size_t)(kb & 1)*HWSZ*32;
    };

    auto halo_load = [&](int kb, uint4v& h) {
        const unsigned short* src = srcof(kb);
        if (hact) h = *(const uint4v*)(hval ? src + hsrc : zp);
    };
    auto halo_write = [&](unsigned short* bin, const uint4v& h) {
        if (hact) *(uint4v*)&bin[hdst] = h;
    };

    // interior: 8 rows x PP col-halves = 8*PP wave-chunks, PP per wave
    // (full 64B granules, inverse-swizzled source, linear LDS dest).
    auto stage_in = [&](int kb, unsigned short* bin) {
        const unsigned short* src = srcof(kb);
#pragma unroll
        for (int j = 0; j < PP; ++j) {
            const int c    = wv + 8*j;           // 0..8*PP-1
            const int row  = (PP == 2) ? 1 + (c >> 1) : 1 + c;
            const int colh = (PP == 2) ? (c & 1) : 0;
            const int gy   = y0 + row - 1;       // in [0,199] always
            const int p0   = row*TC + 1 + colh*16;
            const int pl   = p0 + (lane >> 2);
            const int g    = ((lane & 3) ^ pl ^ (pl >> 2)) & 3;
            const int gx   = x0p + colh*16 + (lane >> 2);
            load_lds16(src + (((size_t)(gy*WW + gx)) << 5) + (g << 3),
                       &bin[(size_t)p0 << 5]);
        }
    };
    auto stage_w = [&](int kb) {
        const unsigned short* wsrc = pw + (size_t)(grp*nkb_stride + kb)*18432;
#pragma unroll
        for (int i = 0; i < 5; ++i) {
            const int u = wv + 8*i;              // 0..39; skip >=36
            if (u < 36)
                load_lds16(wsrc + (size_t)u*512 + (size_t)lane*8, &s_w[(size_t)u*512]);
        }
    };

    f32x4 acc[4][PP];
#pragma unroll
    for (int cf=0; cf<4; ++cf)
#pragma unroll
        for (int p=0; p<PP; ++p) acc[cf][p] = (f32x4){0.f,0.f,0.f,0.f};

    auto compute = [&](const unsigned short* sin) {
        __builtin_amdgcn_s_setprio(1);
#pragma unroll
        for (int ky = 0; ky < 3; ++ky) {
#pragma unroll
            for (int kx = 0; kx < 3; ++kx) {
                const int sh = ky*3 + kx;
                f16x8 aw[4];
#pragma unroll
                for (int cf = 0; cf < 4; ++cf)
                    aw[cf] = *(const f16x8*)&s_w[((sh*4 + cf)*64 + lane)*8];
#pragma unroll
                for (int p = 0; p < PP; ++p) {
                    const int rl = wv + ky;
                    const int cl = 16*p + n16 + kx;
                    const int pos = rl*TC + cl;
                    const int sw = (q ^ pos ^ (pos >> 2)) & 3;
                    f16x8 bfr = *(const f16x8*)&sin[(pos << 5) + (sw << 3)];
#pragma unroll
                    for (int cf = 0; cf < 4; ++cf)
                        acc[cf][p] = __builtin_amdgcn_mfma_f32_16x16x32_f16(
                                         aw[cf], bfr, acc[cf][p], 0, 0, 0);
                }
            }
        }
        __builtin_amdgcn_s_setprio(0);
    };

    uint4v h0, h1;
    stage_in(0, s_in0);          // prologue: kb=0 input + weights + halo
    stage_w(0);
    halo_load(0, h0);

    for (int kb = 0; kb < nkb; kb += 2) {      // nkb even (4 or 6)
        // ===== phase A: buf0 = kb
        halo_write(s_in0, h0);                 // waits h0 (vmcnt dep)
        __syncthreads();                       // kb in+w DMAs landed, halo visible
        halo_load(kb + 1, h1);
        stage_in(kb + 1, s_in1);               // flies across compute
        __builtin_amdgcn_sched_barrier(0);
        compute(s_in0);
        __syncthreads();                       // all waves done reading s_w(kb)
        stage_w(kb + 1);
        // ===== phase B: buf1 = kb+1
        halo_write(s_in1, h1);
        __syncthreads();                       // kb+1 in+w DMAs landed
        if (kb + 2 < nkb) {
            halo_load(kb + 2, h0);
            stage_in(kb + 2, s_in0);
            __builtin_amdgcn_sched_barrier(0);
        }
        compute(s_in1);
        __syncthreads();
        if (kb + 2 < nkb) stage_w(kb + 2);
    }

    // ---- epilogue. C/D: pixel = lane&15, co = (lane>>4)*4 + reg
#pragma unroll
    for (int cf = 0; cf < 4; ++cf) {
        const int half   = cf >> 1;                // 32-ch half within co64
        const int cobase = grp*64 + cf*16 + q*4;   // global co of reg 0
        const int cmod   = (cf & 1)*16 + q*4;      // co within 32-plane
#pragma unroll
        for (int p = 0; p < PP; ++p) {
            const int row = y0 + wv;               // always < 200
            const int col = x0p + 16*p + n16;
            const long pix = (long)row*WW + col;
            const size_t iidx = (((size_t)half*HWSZ + pix) << 5) + cmod;
            float v[4];
#pragma unroll
            for (int r = 0; r < 4; ++r) v[r] = acc[cf][p][r] + bias[cobase + r];

            if (EPI == EPI_MSG) {
                ushort4v xv = *(const ushort4v*)&s0[iidx];
                ushort4v s;
#pragma unroll
                for (int r = 0; r < 4; ++r)
                    s[r] = f2h(0.5f*(h2f(xv[r]) + v[r]));
                *(ushort4v*)&ob[iidx] = s;
            } else if (EPI == EPI_GATES) {
                if (grp == 0) {  // reset block -> rh = sigmoid * h
                    ushort4v hv = e_hb ? *(const ushort4v*)&e_hb[iidx]
                                       : (ushort4v){0,0,0,0};
                    ushort4v s;
#pragma unroll
                    for (int r = 0; r < 4; ++r) {
                        float g = 1.f/(1.f + __expf(-v[r]));
                        s[r] = f2h(g * h2f(hv[r]));
                    }
                    *(ushort4v*)&out_b[iidx] = s;
                } else {         // update block -> updb
                    ushort4v s;
#pragma unroll
                    for (int r = 0; r < 4; ++r)
                        s[r] = f2h(1.f/(1.f + __expf(-v[r])));
                    *(ushort4v*)&out_b2[iidx] = s;
                }
            } else {             // CAND: h_next -> out fp32 planar + hb f16
                ushort4v uv = *(const ushort4v*)&e_updb[iidx];
                ushort4v hv = e_hb ? *(const ushort4v*)&e_hb[iidx]
                                   : (ushort4v){0,0,0,0};
                ushort4v s;
#pragma unroll
                for (int r = 0; r < 4; ++r) {
                    float cnm = tanhf(v[r]);
                    float u   = h2f(uv[r]);
                    float hn  = (1.f - u)*h2f(hv[r]) + u*cnm;
                    out_f[(long)(cobase+r)*HWSZ + pix] = hn;
                    s[r] = f2h(hn);
                }
                *(ushort4v*)&out_b[iidx] = s;
            }
        }
    }
}

// ws (u16 units): xb0_all 4C | aggb3 C | rhb C | updb C | hb C | pw 405504
//   | zp 128  = 72.9 MB.   d_out aliases: xb1_all = out[0..1] (dead until
//   step 0 writes out[0]), aggb[0..2] = out[2..3].
extern "C" void kernel_launch(void* const* d_in, const int* in_sizes, int n_in,
                              void* d_out, int out_size, void* d_ws, size_t ws_size,
                              hipStream_t stream)
{
    const float* x       = (const float*)d_in[0];
    const float* msg_w   = (const float*)d_in[1];
    const float* msg_b   = (const float*)d_in[2];
    const float* gates_w = (const float*)d_in[3];
    const float* gates_b = (const float*)d_in[4];
    const float* can_w   = (const float*)d_in[5];
    const float* can_b   = (const float*)d_in[6];
    float* out = (float*)d_out;

    unsigned short* W       = (unsigned short*)d_ws;
    unsigned short* xb0_all = W;                  // [4][2][HWSZ][32]
    unsigned short* aggb3   = W + 4*CHW;
    unsigned short* rhb     = W + 5*CHW;
    unsigned short* updb    = W + 6*CHW;
    unsigned short* hb      = W + 7*CHW;
    unsigned short* pw      = W + 8*CHW;          // 405504 u16
    unsigned short* pw_msg  = pw;                 // cf4 msg   (1x4)
    unsigned short* pw_gat  = pw + 73728;         // cf4 gates (2x6)
    unsigned short* pw_can  = pw + 294912;        // cf4 cand  (1x6)
    unsigned short* zp      = pw + 405504;        // 128 u16 zero page

    unsigned short* outU16   = (unsigned short*)d_out;
    unsigned short* xb1_all  = outU16;            // 4*CHW u16 = out[0..1]
    unsigned short* aggbase  = outU16 + 4*CHW;    // aggb[0..2] = out[2..3]

    prepack_k<<<dim3(1585), dim3(256), 0, stream>>>(msg_w, gates_w, can_w, pw, zp);
    convert_all_k<<<dim3(17600), dim3(256), 0, stream>>>(x, xb0_all, xb1_all);

    // msg for all 4 t in one dispatch: Cin=[x0|x1], Cout=64 -> aggb[t].
    // TW=32: 1100 blocks, 2/CU, 4 waves/SIMD.
    conv_mfma_k<EPI_MSG,32><<<dim3(11,25,4), dim3(512), 0, stream>>>(
        xb0_all, xb1_all, nullptr, 4, 4, 0, pw_msg, zp, msg_b,
        nullptr, nullptr, nullptr, aggbase, aggb3);

    for (int t = 0; t < 4; ++t) {
        const unsigned short* xt  = xb0_all + (size_t)t*CHW;
        const unsigned short* agt = (t < 3) ? aggbase + (size_t)t*CHW : aggb3;
        const unsigned short* hprev = t ? hb : nullptr;

        if (t == 0) {
            // t=0: h==0 -> reset*h==0 and CAND(nkb=4) never reads rhb;
            // update half only (grp_base=1). TW=16 -> 550 blocks.
            conv_mfma_k<EPI_GATES,16><<<dim3(22,25,1), dim3(512), 0, stream>>>(
                xt, agt, nullptr, 4, 6, 1, pw_gat, zp, gates_b,
                nullptr, nullptr, nullptr, rhb, updb);
        } else {
            // gates: Cin=[x|agg|h], Cout=128; z=0 reset / z=1 update.
            // TW=32: 550 blocks.
            conv_mfma_k<EPI_GATES,32><<<dim3(11,25,2), dim3(512), 0, stream>>>(
                xt, agt, hb, 6, 6, 0, pw_gat, zp, gates_b,
                hprev, nullptr, nullptr, rhb, updb);
        }
        // cand: Cin=[x|agg|rh], Cout=64 -> out[t] fp32 + hb f16.
        // TW=16 -> 550 blocks, 2/CU, 4 waves/SIMD.
        conv_mfma_k<EPI_CAND,16><<<dim3(22,25,1), dim3(512), 0, stream>>>(
            xt, agt, rhb, t ? 6 : 4, 6, 0, pw_can, zp, can_b,
            hprev, updb, out + (size_t)t*CHW, hb, nullptr);
    }
}